// Round 6
// baseline (1072.024 us; speedup 1.0000x reference)
//
#include <hip/hip_runtime.h>

#define DEV __device__ __forceinline__

static constexpr int NB = 16;
static constexpr int N0 = 4096;

// ---- contraction-blocked f32 ops: bit-exact match of numpy's mul/add chain ----
DEV float nf_mul(float a, float b){ float r = a*b; asm volatile("" : "+v"(r)); return r; }
DEV float nf_add(float a, float b){ float r = a+b; asm volatile("" : "+v"(r)); return r; }
DEV float d2nf(float dx, float dy, float dz){
  return nf_add(nf_add(nf_mul(dx,dx), nf_mul(dy,dy)), nf_mul(dz,dz));
}

// ---- wave64 DPP reductions; valid result in lane 63 (old=self -> identity) ----
DEV float dpp_max63(float v){
  int o;
  o = __builtin_amdgcn_update_dpp(__float_as_int(v), __float_as_int(v), 0x118, 0xf, 0xf, false); v = fmaxf(v, __int_as_float(o));
  o = __builtin_amdgcn_update_dpp(__float_as_int(v), __float_as_int(v), 0x114, 0xf, 0xf, false); v = fmaxf(v, __int_as_float(o));
  o = __builtin_amdgcn_update_dpp(__float_as_int(v), __float_as_int(v), 0x112, 0xf, 0xf, false); v = fmaxf(v, __int_as_float(o));
  o = __builtin_amdgcn_update_dpp(__float_as_int(v), __float_as_int(v), 0x111, 0xf, 0xf, false); v = fmaxf(v, __int_as_float(o));
  o = __builtin_amdgcn_update_dpp(__float_as_int(v), __float_as_int(v), 0x142, 0xf, 0xf, false); v = fmaxf(v, __int_as_float(o));
  o = __builtin_amdgcn_update_dpp(__float_as_int(v), __float_as_int(v), 0x143, 0xf, 0xf, false); v = fmaxf(v, __int_as_float(o));
  return v;
}
DEV int dpp_min63(int v){
  int o;
  o = __builtin_amdgcn_update_dpp(v, v, 0x118, 0xf, 0xf, false); v = min(v, o);
  o = __builtin_amdgcn_update_dpp(v, v, 0x114, 0xf, 0xf, false); v = min(v, o);
  o = __builtin_amdgcn_update_dpp(v, v, 0x112, 0xf, 0xf, false); v = min(v, o);
  o = __builtin_amdgcn_update_dpp(v, v, 0x111, 0xf, 0xf, false); v = min(v, o);
  o = __builtin_amdgcn_update_dpp(v, v, 0x142, 0xf, 0xf, false); v = min(v, o);
  o = __builtin_amdgcn_update_dpp(v, v, 0x143, 0xf, 0xf, false); v = min(v, o);
  return v;
}

DEV void tr1(int i, const float* __restrict__ in, float* __restrict__ out, int C, int R){
  int r = i / C, c = i - r*C; out[(size_t)c*R + r] = in[i];
}

// ---------------- front kernel: blocks 0..15 fused FPS; the rest prep ----------------
__global__ __launch_bounds__(256)
void k_front(const float* __restrict__ pc, float4* __restrict__ xyz,
             float4* __restrict__ nx0, float4* __restrict__ nx1,
             const float* __restrict__ w00, float* __restrict__ o00,
             const float* __restrict__ w01, float* __restrict__ o01,
             const float* __restrict__ w10, float* __restrict__ o10,
             const float* __restrict__ w11, float* __restrict__ o11,
             const float* __restrict__ w20, float* __restrict__ o20,
             const float* __restrict__ w21, float* __restrict__ o21)
{
  constexpr int N = 4096, NP = 512, NT = 256, NP2 = 64, NW = NT/64, PT = N/NT;
  if (blockIdx.x >= NB){
    int i = (int)(blockIdx.x - NB)*256 + threadIdx.x;
    if (i < 65536){
      const float* p = pc + (size_t)i*9;
      xyz[i] = make_float4(p[0], p[1], p[2], 0.f);
      return;
    }
    i -= 65536;
    if (i < 576)    { tr1(i, w00, o00, 9, 64);     return; } i -= 576;
    if (i < 8192)   { tr1(i, w01, o01, 64, 128);   return; } i -= 8192;
    if (i < 16768)  { tr1(i, w10, o10, 131, 128);  return; } i -= 16768;
    if (i < 32768)  { tr1(i, w11, o11, 128, 256);  return; } i -= 32768;
    if (i < 132608) { tr1(i, w20, o20, 259, 512);  return; } i -= 132608;
    if (i < 524288) { tr1(i, w21, o21, 512, 1024); return; }
    return;
  }
  // ---------------- FPS: one block per batch, 4 waves ----------------
  __shared__ float sx[N], sy[N], sz[N];
  __shared__ float4 c1p[NP];
  __shared__ unsigned long long xkey[2][NW];
  __shared__ float xc[2][3][NW];
  const int b = blockIdx.x, t = threadIdx.x, lane = t & 63, w = t >> 6;
  const float* src = pc + (size_t)b*N*9;
  float px[PT], py[PT], pz[PT], pd[PT];
  #pragma unroll
  for (int j=0;j<PT;j++){
    int i = t + j*NT;
    const float* a = src + (size_t)i*9;
    float x=a[0], y=a[1], z=a[2];
    px[j]=x; py[j]=y; pz[j]=z; pd[j]=1e10f;
    sx[i]=x; sy[i]=y; sz[i]=z;
  }
  __syncthreads();
  float cx = sx[0], cy = sy[0], cz = sz[0];
  for (int it=0; it<NP; it++){
    if (t==0){
      nx0[(size_t)b*NP + it] = make_float4(cx,cy,cz,0.f);
      c1p[it] = make_float4(cx,cy,cz,0.f);
    }
    float bv = -1.f; int bj = 0;
    #pragma unroll
    for (int j=0;j<PT;j++){
      float d = d2nf(px[j]-cx, py[j]-cy, pz[j]-cz);
      float nd = fminf(pd[j], d);
      pd[j] = nd;
      bool gt = nd > bv;                 // strict > : lowest j kept per lane
      bv = gt ? nd : bv;
      bj = gt ? j  : bj;                 // j is an inline constant operand
    }
    float gmv = dpp_max63(bv);
    float gm = __int_as_float(__builtin_amdgcn_readlane(__float_as_int(gmv), 63));
    int bi = t + bj*NT;
    int cand = (bv == gm) ? bi : 0x7fffffff;
    cand = dpp_min63(cand);
    if (lane == 63){
      int mi = cand;
      xkey[it&1][w] = ((unsigned long long)__float_as_uint(gm) << 32) | (unsigned)~mi;
      xc[it&1][0][w] = sx[mi]; xc[it&1][1][w] = sy[mi]; xc[it&1][2][w] = sz[mi];
    }
    __syncthreads();
    {
      int p = it&1;
      unsigned long long kk = xkey[p][0];
      float ax = xc[p][0][0], ay = xc[p][1][0], az = xc[p][2][0];
      #pragma unroll
      for (int q=1;q<NW;q++){
        unsigned long long kq = xkey[p][q];
        bool g = kq > kk;
        kk = g ? kq : kk;
        ax = g ? xc[p][0][q] : ax;
        ay = g ? xc[p][1][q] : ay;
        az = g ? xc[p][2][q] : az;
      }
      cx = ax; cy = ay; cz = az;
    }
  }
  // ---------------- stage 2: FPS over the 512 stage-1 centers -> 64 ----------------
  {
    float4 p0 = c1p[t], p1 = c1p[t + NT];
    float qx0=p0.x, qy0=p0.y, qz0=p0.z, qd0=1e10f;
    float qx1=p1.x, qy1=p1.y, qz1=p1.z, qd1=1e10f;
    float ax = c1p[0].x, ay = c1p[0].y, az = c1p[0].z;
    for (int it=0; it<NP2; it++){
      if (t==0) nx1[(size_t)b*NP2 + it] = make_float4(ax,ay,az,0.f);
      float d0 = d2nf(qx0-ax, qy0-ay, qz0-az);
      float d1 = d2nf(qx1-ax, qy1-ay, qz1-az);
      qd0 = fminf(qd0, d0);
      qd1 = fminf(qd1, d1);
      float bv = qd0; int bi = t;
      if (qd1 > bv){ bv = qd1; bi = t + NT; }
      float gmv = dpp_max63(bv);
      float gm = __int_as_float(__builtin_amdgcn_readlane(__float_as_int(gmv), 63));
      int cand = (bv == gm) ? bi : 0x7fffffff;
      cand = dpp_min63(cand);
      if (lane == 63){
        int mi = cand;
        float4 pt = c1p[mi];
        xkey[it&1][w] = ((unsigned long long)__float_as_uint(gm) << 32) | (unsigned)~mi;
        xc[it&1][0][w] = pt.x; xc[it&1][1][w] = pt.y; xc[it&1][2][w] = pt.z;
      }
      __syncthreads();
      int p = it&1;
      unsigned long long kk = xkey[p][0];
      float nax = xc[p][0][0], nay = xc[p][1][0], naz = xc[p][2][0];
      #pragma unroll
      for (int q=1;q<NW;q++){
        unsigned long long kq = xkey[p][q];
        bool g = kq > kk;
        kk = g ? kq : kk;
        nax = g ? xc[p][0][q] : nax;
        nay = g ? xc[p][1][q] : nay;
        naz = g ? xc[p][2][q] : naz;
      }
      ax = nax; ay = nay; az = naz;
    }
  }
}

// ---------------- all three ball queries in one launch (wave-per-group) ----------------
__global__ __launch_bounds__(256)
void k_bq_all(const float4* __restrict__ xyz0, const float4* __restrict__ nx0,
              const float4* __restrict__ nx1,
              int* __restrict__ idx0, int* __restrict__ idx1, int* __restrict__ idx2)
{
  int wid = blockIdx.x*4 + (threadIdx.x >> 6);
  int lane = threadIdx.x & 63;
  const float4* xb; float4 c; int* o; int N, K; float r2;
  if (wid < 8192){
    int b = wid >> 9, s = wid & 511;
    xb = xyz0 + (size_t)b*4096; c = nx0[(size_t)b*512 + s];
    o = idx0 + ((size_t)b*512 + s)*32; N = 4096; K = 32; r2 = 0.01f;
  } else if (wid < 9216){
    int u = wid - 8192; int b = u >> 6, s = u & 63;
    xb = nx0 + (size_t)b*512; c = nx1[(size_t)b*64 + s];
    o = idx1 + ((size_t)b*64 + s)*64; N = 512; K = 64; r2 = 0.04f;
  } else {
    int b = wid - 9216;
    xb = nx1 + (size_t)b*64; c = nx1[(size_t)b*64];
    o = idx2 + (size_t)b*64; N = 64; K = 64; r2 = 0.16f;
  }
  int cnt = 0, first = 0;
  bool have_first = false;
  for (int base = 0; base < N; base += 64){
    float4 p = xb[base + lane];
    float d = d2nf(p.x - c.x, p.y - c.y, p.z - c.z);
    bool hit = (d <= r2);
    unsigned long long m = __ballot(hit);
    if (m){
      if (!have_first){ first = base + __ffsll((unsigned long long)m) - 1; have_first = true; }
      if (hit){
        int pos = cnt + __popcll(m & ((1ull << lane) - 1ull));
        if (pos < K) o[pos] = base + lane;
      }
      cnt += __popcll(m);
      if (cnt >= K) break;
    }
  }
  for (int pos = cnt + lane; pos < K; pos += 64) o[pos] = first;
}

// ---------------- SA0 fused: gather + MLP(9->64->128) + maxpool, 8 groups/block ----------------
__global__ __launch_bounds__(256)
void k_sa0(const float4* __restrict__ xyz, const float4* __restrict__ nx0,
           const int* __restrict__ idx0, const float* __restrict__ pc,
           const float* __restrict__ w0tg, const float* __restrict__ g0g, const float* __restrict__ b0g,
           const float* __restrict__ w1tg, const float* __restrict__ g1g, const float* __restrict__ b1g,
           float* __restrict__ f1)
{
  constexpr int K = 32, S = 512, C0 = 64, C1 = 128, G = 8;
  __shared__ float w1t[C0*C1];
  __shared__ float w0t[9*C0];
  __shared__ float gb0[2*C0];
  __shared__ float gb1[2*C1];
  __shared__ float xs[9][K];
  __shared__ float y0[C0][K];
  int t = threadIdx.x;
  for (int i=t;i<C0*C1;i+=256) w1t[i] = w1tg[i];
  for (int i=t;i<9*C0;i+=256)  w0t[i] = w0tg[i];
  if (t < C0){ gb0[t]=g0g[t]; gb0[C0+t]=b0g[t]; }
  if (t < C1){ gb1[t]=g1g[t]; gb1[C1+t]=b1g[t]; }
  int k0 = (t & 7)*4, og = t >> 3;
  for (int gi=0; gi<G; gi++){
    int gid = blockIdx.x*G + gi;
    int b = gid >> 9, s = gid & 511;
    __syncthreads();
    if (t < K){
      int i = idx0[(size_t)gid*K + t];
      float4 cen = nx0[(size_t)b*S + s];
      float4 p = xyz[(size_t)b*N0 + i];
      xs[0][t]=p.x-cen.x; xs[1][t]=p.y-cen.y; xs[2][t]=p.z-cen.z;
      const float* pr = pc + ((size_t)b*N0 + i)*9 + 3;
      #pragma unroll
      for (int f=0;f<6;f++) xs[3+f][t] = pr[f];
    }
    __syncthreads();
    float a0[2][4] = {};
    #pragma unroll
    for (int c=0;c<9;c++){
      float4 xv = *(const float4*)&xs[c][k0];
      #pragma unroll
      for (int j=0;j<2;j++){
        float w = w0t[c*C0 + og*2 + j];
        a0[j][0]+=w*xv.x; a0[j][1]+=w*xv.y; a0[j][2]+=w*xv.z; a0[j][3]+=w*xv.w;
      }
    }
    #pragma unroll
    for (int j=0;j<2;j++){
      int o = og*2 + j;
      float g = gb0[o], bb = gb0[C0+o];
      float4 r;
      r.x=fmaxf(a0[j][0]*g+bb,0.f); r.y=fmaxf(a0[j][1]*g+bb,0.f);
      r.z=fmaxf(a0[j][2]*g+bb,0.f); r.w=fmaxf(a0[j][3]*g+bb,0.f);
      *(float4*)&y0[o][k0] = r;
    }
    __syncthreads();
    float a1[4][4] = {};
    #pragma unroll 4
    for (int c=0;c<C0;c++){
      float4 yv = *(const float4*)&y0[c][k0];
      const float* wp = &w1t[c*C1 + og*4];
      #pragma unroll
      for (int j=0;j<4;j++){
        float w = wp[j];
        a1[j][0]+=w*yv.x; a1[j][1]+=w*yv.y; a1[j][2]+=w*yv.z; a1[j][3]+=w*yv.w;
      }
    }
    #pragma unroll
    for (int j=0;j<4;j++){
      int o = og*4 + j;
      float g = gb1[o], bb = gb1[C1+o];
      float m = fmaxf(fmaxf(a1[j][0]*g+bb, a1[j][1]*g+bb), fmaxf(a1[j][2]*g+bb, a1[j][3]*g+bb));
      m = fmaxf(m, 0.f);
      #pragma unroll
      for (int off=1; off<8; off<<=1) m = fmaxf(m, __shfl_xor(m, off));
      if ((t & 7) == 0) f1[((size_t)b*C1 + o)*S + s] = m;
    }
  }
}

// ---------------- SA1 dense per-point feature GEMM ----------------
__global__ __launch_bounds__(256)
void k_z1(const float* __restrict__ f1, const float* __restrict__ w0t, float* __restrict__ Z1)
{
  int b = blockIdx.z;
  int obase = blockIdx.x*64, ibase = blockIdx.y*64;
  int t = threadIdx.x;
  int i0 = ibase + (t & 15)*4, ol = (t >> 4)*4;
  float acc[4][4] = {};
  #pragma unroll 4
  for (int c=0;c<128;c++){
    float4 fv = *(const float4*)&f1[((size_t)b*128 + c)*512 + i0];
    float4 wv = *(const float4*)&w0t[(size_t)(3+c)*128 + obase + ol];
    float wa[4] = {wv.x, wv.y, wv.z, wv.w};
    float fa[4] = {fv.x, fv.y, fv.z, fv.w};
    #pragma unroll
    for (int j=0;j<4;j++)
      #pragma unroll
      for (int i=0;i<4;i++) acc[j][i] += wa[j]*fa[i];
  }
  #pragma unroll
  for (int j=0;j<4;j++)
    *(float4*)&Z1[((size_t)b*128 + obase + ol + j)*512 + i0] =
        make_float4(acc[j][0], acc[j][1], acc[j][2], acc[j][3]);
}

// ---------------- SA1 fused: gather Z1 + xyz-dot -> y0, MLP1(128->256) + maxpool ----------------
__global__ __launch_bounds__(256)
void k_sa1(const float4* __restrict__ nx0, const float4* __restrict__ nx1,
           const int* __restrict__ idx1, const float* __restrict__ Z1,
           const float* __restrict__ w0t, const float* __restrict__ g0, const float* __restrict__ b0,
           const float* __restrict__ w1t, const float* __restrict__ g1, const float* __restrict__ b1,
           float* __restrict__ f2)
{
  constexpr int K = 64, S = 64, C0 = 128, C1 = 256;
  __shared__ float y0[C0][K];
  __shared__ float gx[3][K];
  __shared__ int sidx[K];
  int gid = blockIdx.x, b = gid >> 6, s = gid & 63;
  int t = threadIdx.x;
  if (t < K) sidx[t] = idx1[(size_t)gid*K + t];
  __syncthreads();
  if (t < K){
    float4 cen = nx1[(size_t)b*S + s];
    float4 p = nx0[(size_t)b*512 + sidx[t]];
    gx[0][t]=p.x-cen.x; gx[1][t]=p.y-cen.y; gx[2][t]=p.z-cen.z;
  }
  __syncthreads();
  int k0 = (t & 15)*4, og = t >> 4;
  {
    float4 x0 = *(const float4*)&gx[0][k0];
    float4 x1 = *(const float4*)&gx[1][k0];
    float4 x2 = *(const float4*)&gx[2][k0];
    int i0=sidx[k0], i1=sidx[k0+1], i2=sidx[k0+2], i3=sidx[k0+3];
    #pragma unroll
    for (int j=0;j<8;j++){
      int o = og*8 + j;
      const float* zr = Z1 + ((size_t)b*C0 + o)*512;
      float wx=w0t[o], wy=w0t[C0+o], wz=w0t[2*C0+o];
      float g=g0[o], bb=b0[o];
      float4 r;
      r.x = fmaxf((zr[i0] + wx*x0.x + wy*x1.x + wz*x2.x)*g + bb, 0.f);
      r.y = fmaxf((zr[i1] + wx*x0.y + wy*x1.y + wz*x2.y)*g + bb, 0.f);
      r.z = fmaxf((zr[i2] + wx*x0.z + wy*x1.z + wz*x2.z)*g + bb, 0.f);
      r.w = fmaxf((zr[i3] + wx*x0.w + wy*x1.w + wz*x2.w)*g + bb, 0.f);
      *(float4*)&y0[o][k0] = r;
    }
  }
  __syncthreads();
  float a1[16][4] = {};
  #pragma unroll 2
  for (int c=0;c<C0;c++){
    float4 yv = *(const float4*)&y0[c][k0];
    const float* wp = &w1t[(size_t)c*C1 + og*16];
    #pragma unroll
    for (int j=0;j<16;j++){
      float w = wp[j];
      a1[j][0]+=w*yv.x; a1[j][1]+=w*yv.y; a1[j][2]+=w*yv.z; a1[j][3]+=w*yv.w;
    }
  }
  #pragma unroll
  for (int j=0;j<16;j++){
    int o = og*16 + j;
    float g=g1[o], bb=b1[o];
    float m = fmaxf(fmaxf(a1[j][0]*g+bb, a1[j][1]*g+bb), fmaxf(a1[j][2]*g+bb, a1[j][3]*g+bb));
    m = fmaxf(m, 0.f);
    #pragma unroll
    for (int off=1; off<16; off<<=1) m = fmaxf(m, __shfl_xor(m, off));
    if ((t & 15) == 0) f2[((size_t)b*C1 + o)*S + s] = m;
  }
}

// ---------------- SA2 gather ----------------
__global__ __launch_bounds__(256)
void k_gather2(const float4* __restrict__ nx1, const int* __restrict__ idx2,
               const float* __restrict__ f2, float* __restrict__ x2)
{
  int b = blockIdx.x, t = threadIdx.x;
  __shared__ int sidx[64];
  if (t < 64) sidx[t] = idx2[b*64 + t];
  __syncthreads();
  float4 cen = nx1[(size_t)b*64];
  float* xo = x2 + (size_t)b*259*64;
  if (t < 64){
    float4 p = nx1[(size_t)b*64 + sidx[t]];
    xo[t] = p.x - cen.x; xo[64 + t] = p.y - cen.y; xo[128 + t] = p.z - cen.z;
  }
  for (int i=t; i<256*64; i+=256){
    int c = i >> 6, k = i & 63;
    xo[(3+c)*64 + k] = f2[((size_t)b*256 + c)*64 + sidx[k]];
  }
}

// ---------------- SA2 layer0 ----------------
__global__ __launch_bounds__(256)
void k_sa2_l0(const float* __restrict__ x2, const float* __restrict__ w0t,
              const float* __restrict__ g0, const float* __restrict__ b0,
              float* __restrict__ y2)
{
  int b = blockIdx.y;
  int obase = blockIdx.x*64;
  int t = threadIdx.x;
  int k0 = (t & 15)*4, ol = (t >> 4)*4;
  const float* xb = x2 + (size_t)b*259*64;
  float acc[4][4] = {};
  #pragma unroll 4
  for (int c=0;c<259;c++){
    float4 xv = *(const float4*)&xb[c*64 + k0];
    float4 wv = *(const float4*)&w0t[(size_t)c*512 + obase + ol];
    float wa[4] = {wv.x, wv.y, wv.z, wv.w};
    float xa[4] = {xv.x, xv.y, xv.z, xv.w};
    #pragma unroll
    for (int j=0;j<4;j++)
      #pragma unroll
      for (int i=0;i<4;i++) acc[j][i] += wa[j]*xa[i];
  }
  #pragma unroll
  for (int j=0;j<4;j++){
    int o = obase + ol + j;
    float g = g0[o], bb = b0[o];
    float4 r;
    r.x=fmaxf(acc[j][0]*g+bb,0.f); r.y=fmaxf(acc[j][1]*g+bb,0.f);
    r.z=fmaxf(acc[j][2]*g+bb,0.f); r.w=fmaxf(acc[j][3]*g+bb,0.f);
    *(float4*)&y2[((size_t)b*512 + o)*64 + k0] = r;
  }
}

// ---------------- SA2 layer1 + maxpool ----------------
__global__ __launch_bounds__(256)
void k_sa2_l1(const float* __restrict__ y2, const float* __restrict__ w1t,
              const float* __restrict__ g1, const float* __restrict__ b1,
              float* __restrict__ f3)
{
  int b = blockIdx.y;
  int obase = blockIdx.x*64;
  int t = threadIdx.x;
  int k0 = (t & 15)*4, ol = (t >> 4)*4;
  const float* yb = y2 + (size_t)b*512*64;
  float acc[4][4] = {};
  #pragma unroll 4
  for (int c=0;c<512;c++){
    float4 yv = *(const float4*)&yb[c*64 + k0];
    float4 wv = *(const float4*)&w1t[(size_t)c*1024 + obase + ol];
    float wa[4] = {wv.x, wv.y, wv.z, wv.w};
    float ya[4] = {yv.x, yv.y, yv.z, yv.w};
    #pragma unroll
    for (int j=0;j<4;j++)
      #pragma unroll
      for (int i=0;i<4;i++) acc[j][i] += wa[j]*ya[i];
  }
  #pragma unroll
  for (int j=0;j<4;j++){
    int o = obase + ol + j;
    float g = g1[o], bb = b1[o];
    float m = fmaxf(fmaxf(acc[j][0]*g+bb, acc[j][1]*g+bb), fmaxf(acc[j][2]*g+bb, acc[j][3]*g+bb));
    m = fmaxf(m, 0.f);
    #pragma unroll
    for (int off=1; off<16; off<<=1) m = fmaxf(m, __shfl_xor(m, off));
    if ((t & 15) == 0) f3[(size_t)b*1024 + o] = m;
  }
}

// ---------------- classifier: one block per batch, all 4 layers ----------------
__global__ __launch_bounds__(256)
void k_cls(const float* __restrict__ f3,
           const float* __restrict__ w0, const float* __restrict__ g0, const float* __restrict__ b0,
           const float* __restrict__ w1, const float* __restrict__ g1, const float* __restrict__ b1,
           const float* __restrict__ w2, const float* __restrict__ g2, const float* __restrict__ b2,
           const float* __restrict__ w3, const float* __restrict__ b3,
           float* __restrict__ out)
{
  __shared__ float xa[1024], xb[1024];
  int b = blockIdx.x, t = threadIdx.x;
  for (int i=t;i<1024;i+=256) xa[i] = f3[(size_t)b*1024 + i];
  __syncthreads();
  for (int o=t;o<1024;o+=256){
    const float4* wr = (const float4*)(w0 + (size_t)o*1024);
    float acc = 0.f;
    #pragma unroll 8
    for (int c=0;c<256;c++){
      float4 wv = wr[c]; float4 xv = *(const float4*)&xa[c*4];
      acc += wv.x*xv.x + wv.y*xv.y + wv.z*xv.z + wv.w*xv.w;
    }
    xb[o] = fmaxf(acc*g0[o] + b0[o], 0.f);
  }
  __syncthreads();
  for (int o=t;o<512;o+=256){
    const float4* wr = (const float4*)(w1 + (size_t)o*1024);
    float acc = 0.f;
    #pragma unroll 8
    for (int c=0;c<256;c++){
      float4 wv = wr[c]; float4 xv = *(const float4*)&xb[c*4];
      acc += wv.x*xv.x + wv.y*xv.y + wv.z*xv.z + wv.w*xv.w;
    }
    xa[o] = fmaxf(acc*g1[o] + b1[o], 0.f);
  }
  __syncthreads();
  if (t < 128){
    const float4* wr = (const float4*)(w2 + (size_t)t*512);
    float acc = 0.f;
    #pragma unroll 8
    for (int c=0;c<128;c++){
      float4 wv = wr[c]; float4 xv = *(const float4*)&xa[c*4];
      acc += wv.x*xv.x + wv.y*xv.y + wv.z*xv.z + wv.w*xv.w;
    }
    xb[t] = fmaxf(acc*g2[t] + b2[t], 0.f);
  }
  __syncthreads();
  if (t < 63){
    const float4* wr = (const float4*)(w3 + (size_t)t*128);
    float acc = 0.f;
    #pragma unroll
    for (int c=0;c<32;c++){
      float4 wv = wr[c]; float4 xv = *(const float4*)&xb[c*4];
      acc += wv.x*xv.x + wv.y*xv.y + wv.z*xv.z + wv.w*xv.w;
    }
    out[(size_t)b*63 + t] = acc + b3[t];
  }
}

extern "C" void kernel_launch(void* const* d_in, const int* in_sizes, int n_in,
                              void* d_out, int out_size, void* d_ws, size_t ws_size,
                              hipStream_t stream)
{
  (void)in_sizes; (void)n_in; (void)out_size; (void)ws_size;
  const float* pc    = (const float*)d_in[0];
  const float* sa0w0 = (const float*)d_in[1];
  const float* sa0g0 = (const float*)d_in[2];
  const float* sa0b0 = (const float*)d_in[3];
  const float* sa0w1 = (const float*)d_in[4];
  const float* sa0g1 = (const float*)d_in[5];
  const float* sa0b1 = (const float*)d_in[6];
  const float* sa1w0 = (const float*)d_in[7];
  const float* sa1g0 = (const float*)d_in[8];
  const float* sa1b0 = (const float*)d_in[9];
  const float* sa1w1 = (const float*)d_in[10];
  const float* sa1g1 = (const float*)d_in[11];
  const float* sa1b1 = (const float*)d_in[12];
  const float* sa2w0 = (const float*)d_in[13];
  const float* sa2g0 = (const float*)d_in[14];
  const float* sa2b0 = (const float*)d_in[15];
  const float* sa2w1 = (const float*)d_in[16];
  const float* sa2g1 = (const float*)d_in[17];
  const float* sa2b1 = (const float*)d_in[18];
  const float* clsw0 = (const float*)d_in[19];
  const float* clsg0 = (const float*)d_in[20];
  const float* clsb0 = (const float*)d_in[21];
  const float* clsw1 = (const float*)d_in[22];
  const float* clsg1 = (const float*)d_in[23];
  const float* clsb1 = (const float*)d_in[24];
  const float* clsw2 = (const float*)d_in[25];
  const float* clsg2 = (const float*)d_in[26];
  const float* clsb2 = (const float*)d_in[27];
  const float* clsw3 = (const float*)d_in[28];
  const float* clsb3 = (const float*)d_in[29];

  char* ws = (char*)d_ws;
  size_t off = 0;
  auto A = [&](size_t bytes)->char* {
    char* p = ws + off;
    off = (off + bytes + 255) & ~(size_t)255;
    return p;
  };
  float4* xyz0 = (float4*)A((size_t)NB*N0*16);
  float4* nx0  = (float4*)A((size_t)NB*512*16);
  float4* nx1  = (float4*)A((size_t)NB*64*16);
  int*   idx0  = (int*)  A((size_t)NB*512*32*4);
  int*   idx1  = (int*)  A((size_t)NB*64*64*4);
  int*   idx2  = (int*)  A((size_t)NB*64*4);
  float* f1    = (float*)A((size_t)NB*128*512*4);
  float* Z1    = (float*)A((size_t)NB*128*512*4);
  float* f2    = (float*)A((size_t)NB*256*64*4);
  float* x2    = (float*)A((size_t)NB*259*64*4);
  float* y2    = (float*)A((size_t)NB*512*64*4);
  float* f3    = (float*)A((size_t)NB*1024*4);
  float* w0t0  = (float*)A((size_t)9*64*4);
  float* w1t0  = (float*)A((size_t)64*128*4);
  float* w0t1  = (float*)A((size_t)131*128*4);
  float* w1t1  = (float*)A((size_t)128*256*4);
  float* w0t2  = (float*)A((size_t)259*512*4);
  float* w1t2  = (float*)A((size_t)512*1024*4);

  // ---- front: 16 FPS blocks + 3050 prep blocks in ONE launch ----
  k_front<<<NB + 3050, 256, 0, stream>>>(pc, xyz0, nx0, nx1,
      sa0w0, w0t0, sa0w1, w1t0, sa1w0, w0t1, sa1w1, w1t1, sa2w0, w0t2, sa2w1, w1t2);

  // ---- all ball queries ----
  k_bq_all<<<2308, 256, 0, stream>>>(xyz0, nx0, nx1, idx0, idx1, idx2);

  // ---- SA0 ----
  k_sa0<<<(NB*512)/8, 256, 0, stream>>>(xyz0, nx0, idx0, pc,
                                        w0t0, sa0g0, sa0b0, w1t0, sa0g1, sa0b1, f1);
  // ---- SA1 ----
  k_z1<<<dim3(2, 8, NB), 256, 0, stream>>>(f1, w0t1, Z1);
  k_sa1<<<NB*64, 256, 0, stream>>>(nx0, nx1, idx1, Z1,
                                   w0t1, sa1g0, sa1b0, w1t1, sa1g1, sa1b1, f2);
  // ---- SA2 ----
  k_gather2<<<NB, 256, 0, stream>>>(nx1, idx2, f2, x2);
  k_sa2_l0<<<dim3(8, NB), 256, 0, stream>>>(x2, w0t2, sa2g0, sa2b0, y2);
  k_sa2_l1<<<dim3(16, NB), 256, 0, stream>>>(y2, w1t2, sa2g1, sa2b1, f3);
  // ---- classifier ----
  k_cls<<<NB, 256, 0, stream>>>(f3, clsw0, clsg0, clsb0, clsw1, clsg1, clsb1,
                                clsw2, clsg2, clsb2, clsw3, clsb3, (float*)d_out);
}

// Round 7
// 832.969 us; speedup vs baseline: 1.2870x; 1.2870x over previous
//
#include <hip/hip_runtime.h>

#define DEV __device__ __forceinline__

static constexpr int NB = 16;
static constexpr int N0 = 4096;

// ---- unfused f32 distance: IEEE mul/add chain, left-assoc, no FMA contraction.
// Bit-exact match of numpy's ((dx*dx + dy*dy) + dz*dz).
DEV float d2c(float dx, float dy, float dz){
#pragma clang fp contract(off)
  return dx*dx + dy*dy + dz*dz;
}

// ---- wave64 max-reduce of packed u64 key; result lands in lane 63 ----
// key = (f32 bits of dist << 32) | ~index  -> max key == (max dist, tie: min index)
#define DPP_STEP(CTRL) { \
  int hi=(int)(k>>32), lo=(int)k; \
  int ohi=__builtin_amdgcn_update_dpp(hi,hi,CTRL,0xf,0xf,false); \
  int olo=__builtin_amdgcn_update_dpp(lo,lo,CTRL,0xf,0xf,false); \
  unsigned long long ok=((unsigned long long)(unsigned)ohi<<32)|(unsigned)olo; \
  if (ok>k) k=ok; }

DEV unsigned long long dpp_max_key63(unsigned long long k){
  DPP_STEP(0x118)  // row_shr:8
  DPP_STEP(0x114)  // row_shr:4
  DPP_STEP(0x112)  // row_shr:2
  DPP_STEP(0x111)  // row_shr:1
  DPP_STEP(0x142)  // row_bcast:15
  DPP_STEP(0x143)  // row_bcast:31
  return k;
}

DEV void tr1(int i, const float* __restrict__ in, float* __restrict__ out, int C, int R){
  int r = i / C, c = i - r*C; out[(size_t)c*R + r] = in[i];
}

// ---------------- front kernel: blocks 0..15 fused FPS; the rest prep ----------------
__global__ __launch_bounds__(256)
void k_front(const float* __restrict__ pc, float4* __restrict__ xyz,
             float4* __restrict__ nx0, float4* __restrict__ nx1,
             const float* __restrict__ w00, float* __restrict__ o00,
             const float* __restrict__ w01, float* __restrict__ o01,
             const float* __restrict__ w10, float* __restrict__ o10,
             const float* __restrict__ w11, float* __restrict__ o11,
             const float* __restrict__ w20, float* __restrict__ o20,
             const float* __restrict__ w21, float* __restrict__ o21)
{
  constexpr int N = 4096, NP = 512, NT = 256, NP2 = 64, NW = NT/64, PT = N/NT;
  if (blockIdx.x >= NB){
    int i = (int)(blockIdx.x - NB)*256 + threadIdx.x;
    if (i < 65536){
      const float* p = pc + (size_t)i*9;
      xyz[i] = make_float4(p[0], p[1], p[2], 0.f);
      return;
    }
    i -= 65536;
    if (i < 576)    { tr1(i, w00, o00, 9, 64);     return; } i -= 576;
    if (i < 8192)   { tr1(i, w01, o01, 64, 128);   return; } i -= 8192;
    if (i < 16768)  { tr1(i, w10, o10, 131, 128);  return; } i -= 16768;
    if (i < 32768)  { tr1(i, w11, o11, 128, 256);  return; } i -= 32768;
    if (i < 132608) { tr1(i, w20, o20, 259, 512);  return; } i -= 132608;
    if (i < 524288) { tr1(i, w21, o21, 512, 1024); return; }
    return;
  }
  // ---------------- FPS: one block per batch, 4 waves ----------------
  __shared__ float4 sp[N];                 // points as float4: 1 ds_read_b128 center fetch
  __shared__ float4 c1p[NP];
  __shared__ unsigned long long exch[2][NW];
  const int b = blockIdx.x, t = threadIdx.x, lane = t & 63, w = t >> 6;
  const float* src = pc + (size_t)b*N*9;
  float px[PT], py[PT], pz[PT], pd[PT];
  unsigned nlo[PT];
  #pragma unroll
  for (int j=0;j<PT;j++){
    int i = t + j*NT;
    const float* a = src + (size_t)i*9;
    float x=a[0], y=a[1], z=a[2];
    px[j]=x; py[j]=y; pz[j]=z; pd[j]=1e10f;
    nlo[j] = ~(unsigned)i;
    sp[i] = make_float4(x,y,z,0.f);
  }
  __syncthreads();
  float cx = sp[0].x, cy = sp[0].y, cz = sp[0].z;
  for (int it=0; it<NP; it++){
    if (t==0){
      nx0[(size_t)b*NP + it] = make_float4(cx,cy,cz,0.f);
      c1p[it] = make_float4(cx,cy,cz,0.f);
    }
    unsigned long long best = 0;
    #pragma unroll
    for (int j=0;j<PT;j++){
      float d = d2c(px[j]-cx, py[j]-cy, pz[j]-cz);
      float nd = fminf(pd[j], d);
      pd[j] = nd;
      unsigned long long k = ((unsigned long long)__float_as_uint(nd)<<32) | nlo[j];
      if (k > best) best = k;
    }
    { unsigned long long k = best; DPP_STEP(0x118) DPP_STEP(0x114) DPP_STEP(0x112)
      DPP_STEP(0x111) DPP_STEP(0x142) DPP_STEP(0x143) best = k; }
    if (lane == 63) exch[it&1][w] = best;
    __syncthreads();
    unsigned long long g = exch[it&1][0];
    #pragma unroll
    for (int q=1;q<NW;q++){ unsigned long long e = exch[it&1][q]; if (e > g) g = e; }
    int far = (int)~(unsigned)g;
    float4 c = sp[far];
    cx = c.x; cy = c.y; cz = c.z;
  }
  // ---------------- stage 2: FPS over the 512 stage-1 centers -> 64 ----------------
  {
    float4 p0 = c1p[t], p1 = c1p[t + NT];
    float qd0 = 1e10f, qd1 = 1e10f;
    unsigned nl0 = ~(unsigned)t, nl1 = ~(unsigned)(t + NT);
    float ax = c1p[0].x, ay = c1p[0].y, az = c1p[0].z;
    for (int it=0; it<NP2; it++){
      if (t==0) nx1[(size_t)b*NP2 + it] = make_float4(ax,ay,az,0.f);
      float d0 = d2c(p0.x-ax, p0.y-ay, p0.z-az);
      float d1 = d2c(p1.x-ax, p1.y-ay, p1.z-az);
      qd0 = fminf(qd0, d0);
      qd1 = fminf(qd1, d1);
      unsigned long long best = ((unsigned long long)__float_as_uint(qd0)<<32) | nl0;
      unsigned long long k1   = ((unsigned long long)__float_as_uint(qd1)<<32) | nl1;
      if (k1 > best) best = k1;
      { unsigned long long k = best; DPP_STEP(0x118) DPP_STEP(0x114) DPP_STEP(0x112)
        DPP_STEP(0x111) DPP_STEP(0x142) DPP_STEP(0x143) best = k; }
      if (lane == 63) exch[it&1][w] = best;
      __syncthreads();
      unsigned long long g = exch[it&1][0];
      #pragma unroll
      for (int q=1;q<NW;q++){ unsigned long long e = exch[it&1][q]; if (e > g) g = e; }
      int far = (int)~(unsigned)g;
      float4 c = c1p[far];
      ax = c.x; ay = c.y; az = c.z;
    }
  }
}

// ---------------- all three ball queries in one launch (wave-per-group) ----------------
__global__ __launch_bounds__(256)
void k_bq_all(const float4* __restrict__ xyz0, const float4* __restrict__ nx0,
              const float4* __restrict__ nx1,
              int* __restrict__ idx0, int* __restrict__ idx1, int* __restrict__ idx2)
{
  int wid = blockIdx.x*4 + (threadIdx.x >> 6);
  int lane = threadIdx.x & 63;
  const float4* xb; float4 c; int* o; int N, K; float r2;
  if (wid < 8192){
    int b = wid >> 9, s = wid & 511;
    xb = xyz0 + (size_t)b*4096; c = nx0[(size_t)b*512 + s];
    o = idx0 + ((size_t)b*512 + s)*32; N = 4096; K = 32; r2 = 0.01f;
  } else if (wid < 9216){
    int u = wid - 8192; int b = u >> 6, s = u & 63;
    xb = nx0 + (size_t)b*512; c = nx1[(size_t)b*64 + s];
    o = idx1 + ((size_t)b*64 + s)*64; N = 512; K = 64; r2 = 0.04f;
  } else {
    int b = wid - 9216;
    xb = nx1 + (size_t)b*64; c = nx1[(size_t)b*64];
    o = idx2 + (size_t)b*64; N = 64; K = 64; r2 = 0.16f;
  }
  int cnt = 0, first = 0;
  bool have_first = false;
  for (int base = 0; base < N; base += 64){
    float4 p = xb[base + lane];
    float d = d2c(p.x - c.x, p.y - c.y, p.z - c.z);
    bool hit = (d <= r2);
    unsigned long long m = __ballot(hit);
    if (m){
      if (!have_first){ first = base + __ffsll((unsigned long long)m) - 1; have_first = true; }
      if (hit){
        int pos = cnt + __popcll(m & ((1ull << lane) - 1ull));
        if (pos < K) o[pos] = base + lane;
      }
      cnt += __popcll(m);
      if (cnt >= K) break;
    }
  }
  for (int pos = cnt + lane; pos < K; pos += 64) o[pos] = first;
}

// ---------------- SA0 fused: gather + MLP(9->64->128) + maxpool, 8 groups/block ----------------
__global__ __launch_bounds__(256)
void k_sa0(const float4* __restrict__ xyz, const float4* __restrict__ nx0,
           const int* __restrict__ idx0, const float* __restrict__ pc,
           const float* __restrict__ w0tg, const float* __restrict__ g0g, const float* __restrict__ b0g,
           const float* __restrict__ w1tg, const float* __restrict__ g1g, const float* __restrict__ b1g,
           float* __restrict__ f1)
{
  constexpr int K = 32, S = 512, C0 = 64, C1 = 128, G = 8;
  __shared__ float w1t[C0*C1];
  __shared__ float w0t[9*C0];
  __shared__ float gb0[2*C0];
  __shared__ float gb1[2*C1];
  __shared__ float xs[9][K];
  __shared__ float y0[C0][K];
  int t = threadIdx.x;
  for (int i=t;i<C0*C1;i+=256) w1t[i] = w1tg[i];
  for (int i=t;i<9*C0;i+=256)  w0t[i] = w0tg[i];
  if (t < C0){ gb0[t]=g0g[t]; gb0[C0+t]=b0g[t]; }
  if (t < C1){ gb1[t]=g1g[t]; gb1[C1+t]=b1g[t]; }
  int k0 = (t & 7)*4, og = t >> 3;
  for (int gi=0; gi<G; gi++){
    int gid = blockIdx.x*G + gi;
    int b = gid >> 9, s = gid & 511;
    __syncthreads();
    if (t < K){
      int i = idx0[(size_t)gid*K + t];
      float4 cen = nx0[(size_t)b*S + s];
      float4 p = xyz[(size_t)b*N0 + i];
      xs[0][t]=p.x-cen.x; xs[1][t]=p.y-cen.y; xs[2][t]=p.z-cen.z;
      const float* pr = pc + ((size_t)b*N0 + i)*9 + 3;
      #pragma unroll
      for (int f=0;f<6;f++) xs[3+f][t] = pr[f];
    }
    __syncthreads();
    float a0[2][4] = {};
    #pragma unroll
    for (int c=0;c<9;c++){
      float4 xv = *(const float4*)&xs[c][k0];
      #pragma unroll
      for (int j=0;j<2;j++){
        float w = w0t[c*C0 + og*2 + j];
        a0[j][0]+=w*xv.x; a0[j][1]+=w*xv.y; a0[j][2]+=w*xv.z; a0[j][3]+=w*xv.w;
      }
    }
    #pragma unroll
    for (int j=0;j<2;j++){
      int o = og*2 + j;
      float g = gb0[o], bb = gb0[C0+o];
      float4 r;
      r.x=fmaxf(a0[j][0]*g+bb,0.f); r.y=fmaxf(a0[j][1]*g+bb,0.f);
      r.z=fmaxf(a0[j][2]*g+bb,0.f); r.w=fmaxf(a0[j][3]*g+bb,0.f);
      *(float4*)&y0[o][k0] = r;
    }
    __syncthreads();
    float a1[4][4] = {};
    #pragma unroll 4
    for (int c=0;c<C0;c++){
      float4 yv = *(const float4*)&y0[c][k0];
      const float* wp = &w1t[c*C1 + og*4];
      #pragma unroll
      for (int j=0;j<4;j++){
        float w = wp[j];
        a1[j][0]+=w*yv.x; a1[j][1]+=w*yv.y; a1[j][2]+=w*yv.z; a1[j][3]+=w*yv.w;
      }
    }
    #pragma unroll
    for (int j=0;j<4;j++){
      int o = og*4 + j;
      float g = gb1[o], bb = gb1[C1+o];
      float m = fmaxf(fmaxf(a1[j][0]*g+bb, a1[j][1]*g+bb), fmaxf(a1[j][2]*g+bb, a1[j][3]*g+bb));
      m = fmaxf(m, 0.f);
      #pragma unroll
      for (int off=1; off<8; off<<=1) m = fmaxf(m, __shfl_xor(m, off));
      if ((t & 7) == 0) f1[((size_t)b*C1 + o)*S + s] = m;
    }
  }
}

// ---------------- SA1 dense per-point feature GEMM ----------------
__global__ __launch_bounds__(256)
void k_z1(const float* __restrict__ f1, const float* __restrict__ w0t, float* __restrict__ Z1)
{
  int b = blockIdx.z;
  int obase = blockIdx.x*64, ibase = blockIdx.y*64;
  int t = threadIdx.x;
  int i0 = ibase + (t & 15)*4, ol = (t >> 4)*4;
  float acc[4][4] = {};
  #pragma unroll 4
  for (int c=0;c<128;c++){
    float4 fv = *(const float4*)&f1[((size_t)b*128 + c)*512 + i0];
    float4 wv = *(const float4*)&w0t[(size_t)(3+c)*128 + obase + ol];
    float wa[4] = {wv.x, wv.y, wv.z, wv.w};
    float fa[4] = {fv.x, fv.y, fv.z, fv.w};
    #pragma unroll
    for (int j=0;j<4;j++)
      #pragma unroll
      for (int i=0;i<4;i++) acc[j][i] += wa[j]*fa[i];
  }
  #pragma unroll
  for (int j=0;j<4;j++)
    *(float4*)&Z1[((size_t)b*128 + obase + ol + j)*512 + i0] =
        make_float4(acc[j][0], acc[j][1], acc[j][2], acc[j][3]);
}

// ---------------- SA1 fused: gather Z1 + xyz-dot -> y0, MLP1(128->256) + maxpool ----------------
__global__ __launch_bounds__(256)
void k_sa1(const float4* __restrict__ nx0, const float4* __restrict__ nx1,
           const int* __restrict__ idx1, const float* __restrict__ Z1,
           const float* __restrict__ w0t, const float* __restrict__ g0, const float* __restrict__ b0,
           const float* __restrict__ w1t, const float* __restrict__ g1, const float* __restrict__ b1,
           float* __restrict__ f2)
{
  constexpr int K = 64, S = 64, C0 = 128, C1 = 256;
  __shared__ float y0[C0][K];
  __shared__ float gx[3][K];
  __shared__ int sidx[K];
  int gid = blockIdx.x, b = gid >> 6, s = gid & 63;
  int t = threadIdx.x;
  if (t < K) sidx[t] = idx1[(size_t)gid*K + t];
  __syncthreads();
  if (t < K){
    float4 cen = nx1[(size_t)b*S + s];
    float4 p = nx0[(size_t)b*512 + sidx[t]];
    gx[0][t]=p.x-cen.x; gx[1][t]=p.y-cen.y; gx[2][t]=p.z-cen.z;
  }
  __syncthreads();
  int k0 = (t & 15)*4, og = t >> 4;
  {
    float4 x0 = *(const float4*)&gx[0][k0];
    float4 x1 = *(const float4*)&gx[1][k0];
    float4 x2 = *(const float4*)&gx[2][k0];
    int i0=sidx[k0], i1=sidx[k0+1], i2=sidx[k0+2], i3=sidx[k0+3];
    #pragma unroll
    for (int j=0;j<8;j++){
      int o = og*8 + j;
      const float* zr = Z1 + ((size_t)b*C0 + o)*512;
      float wx=w0t[o], wy=w0t[C0+o], wz=w0t[2*C0+o];
      float g=g0[o], bb=b0[o];
      float4 r;
      r.x = fmaxf((zr[i0] + wx*x0.x + wy*x1.x + wz*x2.x)*g + bb, 0.f);
      r.y = fmaxf((zr[i1] + wx*x0.y + wy*x1.y + wz*x2.y)*g + bb, 0.f);
      r.z = fmaxf((zr[i2] + wx*x0.z + wy*x1.z + wz*x2.z)*g + bb, 0.f);
      r.w = fmaxf((zr[i3] + wx*x0.w + wy*x1.w + wz*x2.w)*g + bb, 0.f);
      *(float4*)&y0[o][k0] = r;
    }
  }
  __syncthreads();
  float a1[16][4] = {};
  #pragma unroll 2
  for (int c=0;c<C0;c++){
    float4 yv = *(const float4*)&y0[c][k0];
    const float* wp = &w1t[(size_t)c*C1 + og*16];
    #pragma unroll
    for (int j=0;j<16;j++){
      float w = wp[j];
      a1[j][0]+=w*yv.x; a1[j][1]+=w*yv.y; a1[j][2]+=w*yv.z; a1[j][3]+=w*yv.w;
    }
  }
  #pragma unroll
  for (int j=0;j<16;j++){
    int o = og*16 + j;
    float g=g1[o], bb=b1[o];
    float m = fmaxf(fmaxf(a1[j][0]*g+bb, a1[j][1]*g+bb), fmaxf(a1[j][2]*g+bb, a1[j][3]*g+bb));
    m = fmaxf(m, 0.f);
    #pragma unroll
    for (int off=1; off<16; off<<=1) m = fmaxf(m, __shfl_xor(m, off));
    if ((t & 15) == 0) f2[((size_t)b*C1 + o)*S + s] = m;
  }
}

// ---------------- SA2 gather ----------------
__global__ __launch_bounds__(256)
void k_gather2(const float4* __restrict__ nx1, const int* __restrict__ idx2,
               const float* __restrict__ f2, float* __restrict__ x2)
{
  int b = blockIdx.x, t = threadIdx.x;
  __shared__ int sidx[64];
  if (t < 64) sidx[t] = idx2[b*64 + t];
  __syncthreads();
  float4 cen = nx1[(size_t)b*64];
  float* xo = x2 + (size_t)b*259*64;
  if (t < 64){
    float4 p = nx1[(size_t)b*64 + sidx[t]];
    xo[t] = p.x - cen.x; xo[64 + t] = p.y - cen.y; xo[128 + t] = p.z - cen.z;
  }
  for (int i=t; i<256*64; i+=256){
    int c = i >> 6, k = i & 63;
    xo[(3+c)*64 + k] = f2[((size_t)b*256 + c)*64 + sidx[k]];
  }
}

// ---------------- SA2 layer0 ----------------
__global__ __launch_bounds__(256)
void k_sa2_l0(const float* __restrict__ x2, const float* __restrict__ w0t,
              const float* __restrict__ g0, const float* __restrict__ b0,
              float* __restrict__ y2)
{
  int b = blockIdx.y;
  int obase = blockIdx.x*64;
  int t = threadIdx.x;
  int k0 = (t & 15)*4, ol = (t >> 4)*4;
  const float* xb = x2 + (size_t)b*259*64;
  float acc[4][4] = {};
  #pragma unroll 4
  for (int c=0;c<259;c++){
    float4 xv = *(const float4*)&xb[c*64 + k0];
    float4 wv = *(const float4*)&w0t[(size_t)c*512 + obase + ol];
    float wa[4] = {wv.x, wv.y, wv.z, wv.w};
    float xa[4] = {xv.x, xv.y, xv.z, xv.w};
    #pragma unroll
    for (int j=0;j<4;j++)
      #pragma unroll
      for (int i=0;i<4;i++) acc[j][i] += wa[j]*xa[i];
  }
  #pragma unroll
  for (int j=0;j<4;j++){
    int o = obase + ol + j;
    float g = g0[o], bb = b0[o];
    float4 r;
    r.x=fmaxf(acc[j][0]*g+bb,0.f); r.y=fmaxf(acc[j][1]*g+bb,0.f);
    r.z=fmaxf(acc[j][2]*g+bb,0.f); r.w=fmaxf(acc[j][3]*g+bb,0.f);
    *(float4*)&y2[((size_t)b*512 + o)*64 + k0] = r;
  }
}

// ---------------- SA2 layer1 + maxpool ----------------
__global__ __launch_bounds__(256)
void k_sa2_l1(const float* __restrict__ y2, const float* __restrict__ w1t,
              const float* __restrict__ g1, const float* __restrict__ b1,
              float* __restrict__ f3)
{
  int b = blockIdx.y;
  int obase = blockIdx.x*64;
  int t = threadIdx.x;
  int k0 = (t & 15)*4, ol = (t >> 4)*4;
  const float* yb = y2 + (size_t)b*512*64;
  float acc[4][4] = {};
  #pragma unroll 4
  for (int c=0;c<512;c++){
    float4 yv = *(const float4*)&yb[c*64 + k0];
    float4 wv = *(const float4*)&w1t[(size_t)c*1024 + obase + ol];
    float wa[4] = {wv.x, wv.y, wv.z, wv.w};
    float ya[4] = {yv.x, yv.y, yv.z, yv.w};
    #pragma unroll
    for (int j=0;j<4;j++)
      #pragma unroll
      for (int i=0;i<4;i++) acc[j][i] += wa[j]*ya[i];
  }
  #pragma unroll
  for (int j=0;j<4;j++){
    int o = obase + ol + j;
    float g = g1[o], bb = b1[o];
    float m = fmaxf(fmaxf(acc[j][0]*g+bb, acc[j][1]*g+bb), fmaxf(acc[j][2]*g+bb, acc[j][3]*g+bb));
    m = fmaxf(m, 0.f);
    #pragma unroll
    for (int off=1; off<16; off<<=1) m = fmaxf(m, __shfl_xor(m, off));
    if ((t & 15) == 0) f3[(size_t)b*1024 + o] = m;
  }
}

// ---------------- classifier: wide GEMV layers ----------------
template<bool RELU>
__global__ __launch_bounds__(256)
void k_lin(const float* __restrict__ x, const float* __restrict__ w,
           const float* __restrict__ g, const float* __restrict__ bb,
           float* __restrict__ y, int Cin, int Cout)
{
  __shared__ float xs[1024];
  int b = blockIdx.y, t = threadIdx.x;
  const float* xb = x + (size_t)b*Cin;
  for (int i=t;i<Cin;i+=256) xs[i] = xb[i];
  __syncthreads();
  int o = blockIdx.x*256 + t;
  if (o < Cout){
    const float4* wr = (const float4*)(w + (size_t)o*Cin);
    float acc = 0.f;
    #pragma unroll 8
    for (int c=0;c<Cin/4;c++){
      float4 wv = wr[c]; float4 xv = *(const float4*)&xs[c*4];
      acc += wv.x*xv.x + wv.y*xv.y + wv.z*xv.z + wv.w*xv.w;
    }
    float r;
    if (RELU) r = fmaxf(acc*g[o] + bb[o], 0.f);
    else      r = acc + bb[o];
    y[(size_t)b*Cout + o] = r;
  }
}

extern "C" void kernel_launch(void* const* d_in, const int* in_sizes, int n_in,
                              void* d_out, int out_size, void* d_ws, size_t ws_size,
                              hipStream_t stream)
{
  (void)in_sizes; (void)n_in; (void)out_size; (void)ws_size;
  const float* pc    = (const float*)d_in[0];
  const float* sa0w0 = (const float*)d_in[1];
  const float* sa0g0 = (const float*)d_in[2];
  const float* sa0b0 = (const float*)d_in[3];
  const float* sa0w1 = (const float*)d_in[4];
  const float* sa0g1 = (const float*)d_in[5];
  const float* sa0b1 = (const float*)d_in[6];
  const float* sa1w0 = (const float*)d_in[7];
  const float* sa1g0 = (const float*)d_in[8];
  const float* sa1b0 = (const float*)d_in[9];
  const float* sa1w1 = (const float*)d_in[10];
  const float* sa1g1 = (const float*)d_in[11];
  const float* sa1b1 = (const float*)d_in[12];
  const float* sa2w0 = (const float*)d_in[13];
  const float* sa2g0 = (const float*)d_in[14];
  const float* sa2b0 = (const float*)d_in[15];
  const float* sa2w1 = (const float*)d_in[16];
  const float* sa2g1 = (const float*)d_in[17];
  const float* sa2b1 = (const float*)d_in[18];
  const float* clsw0 = (const float*)d_in[19];
  const float* clsg0 = (const float*)d_in[20];
  const float* clsb0 = (const float*)d_in[21];
  const float* clsw1 = (const float*)d_in[22];
  const float* clsg1 = (const float*)d_in[23];
  const float* clsb1 = (const float*)d_in[24];
  const float* clsw2 = (const float*)d_in[25];
  const float* clsg2 = (const float*)d_in[26];
  const float* clsb2 = (const float*)d_in[27];
  const float* clsw3 = (const float*)d_in[28];
  const float* clsb3 = (const float*)d_in[29];

  char* ws = (char*)d_ws;
  size_t off = 0;
  auto A = [&](size_t bytes)->char* {
    char* p = ws + off;
    off = (off + bytes + 255) & ~(size_t)255;
    return p;
  };
  float4* xyz0 = (float4*)A((size_t)NB*N0*16);
  float4* nx0  = (float4*)A((size_t)NB*512*16);
  float4* nx1  = (float4*)A((size_t)NB*64*16);
  int*   idx0  = (int*)  A((size_t)NB*512*32*4);
  int*   idx1  = (int*)  A((size_t)NB*64*64*4);
  int*   idx2  = (int*)  A((size_t)NB*64*4);
  float* f1    = (float*)A((size_t)NB*128*512*4);
  float* Z1    = (float*)A((size_t)NB*128*512*4);
  float* f2    = (float*)A((size_t)NB*256*64*4);
  float* x2    = (float*)A((size_t)NB*259*64*4);
  float* y2    = (float*)A((size_t)NB*512*64*4);
  float* f3    = (float*)A((size_t)NB*1024*4);
  float* cb0   = (float*)A((size_t)NB*1024*4);
  float* cb1   = (float*)A((size_t)NB*512*4);
  float* cb2   = (float*)A((size_t)NB*128*4);
  float* w0t0  = (float*)A((size_t)9*64*4);
  float* w1t0  = (float*)A((size_t)64*128*4);
  float* w0t1  = (float*)A((size_t)131*128*4);
  float* w1t1  = (float*)A((size_t)128*256*4);
  float* w0t2  = (float*)A((size_t)259*512*4);
  float* w1t2  = (float*)A((size_t)512*1024*4);

  // ---- front: 16 FPS blocks + 3050 prep blocks in ONE launch ----
  k_front<<<NB + 3050, 256, 0, stream>>>(pc, xyz0, nx0, nx1,
      sa0w0, w0t0, sa0w1, w1t0, sa1w0, w0t1, sa1w1, w1t1, sa2w0, w0t2, sa2w1, w1t2);

  // ---- all ball queries ----
  k_bq_all<<<2308, 256, 0, stream>>>(xyz0, nx0, nx1, idx0, idx1, idx2);

  // ---- SA0 ----
  k_sa0<<<(NB*512)/8, 256, 0, stream>>>(xyz0, nx0, idx0, pc,
                                        w0t0, sa0g0, sa0b0, w1t0, sa0g1, sa0b1, f1);
  // ---- SA1 ----
  k_z1<<<dim3(2, 8, NB), 256, 0, stream>>>(f1, w0t1, Z1);
  k_sa1<<<NB*64, 256, 0, stream>>>(nx0, nx1, idx1, Z1,
                                   w0t1, sa1g0, sa1b0, w1t1, sa1g1, sa1b1, f2);
  // ---- SA2 ----
  k_gather2<<<NB, 256, 0, stream>>>(nx1, idx2, f2, x2);
  k_sa2_l0<<<dim3(8, NB), 256, 0, stream>>>(x2, w0t2, sa2g0, sa2b0, y2);
  k_sa2_l1<<<dim3(16, NB), 256, 0, stream>>>(y2, w1t2, sa2g1, sa2b1, f3);
  // ---- classifier ----
  k_lin<true ><<<dim3(4, NB), 256, 0, stream>>>(f3,  clsw0, clsg0, clsb0, cb0, 1024, 1024);
  k_lin<true ><<<dim3(2, NB), 256, 0, stream>>>(cb0, clsw1, clsg1, clsb1, cb1, 1024, 512);
  k_lin<true ><<<dim3(1, NB), 256, 0, stream>>>(cb1, clsw2, clsg2, clsb2, cb2, 512, 128);
  k_lin<false><<<dim3(1, NB), 256, 0, stream>>>(cb2, clsw3, clsb3, clsb3, (float*)d_out, 128, 63);
}

// Round 10
// 825.298 us; speedup vs baseline: 1.2990x; 1.0093x over previous
//
#include <hip/hip_runtime.h>

#define DEV __device__ __forceinline__

static constexpr int NB = 16;
static constexpr int N0 = 4096;

typedef float v2f __attribute__((ext_vector_type(2)));

// ---- unfused f32 distance: IEEE mul/add chain, left-assoc, no FMA contraction.
// Bit-exact match of numpy's ((dx*dx + dy*dy) + dz*dz).
DEV float d2c(float dx, float dy, float dz){
#pragma clang fp contract(off)
  return dx*dx + dy*dy + dz*dz;
}
// packed variant: v_pk_mul/add are exact per-lane IEEE ops -> numerics == scalar
DEV v2f d2v(v2f dx, v2f dy, v2f dz){
#pragma clang fp contract(off)
  return dx*dx + dy*dy + dz*dz;
}

// ---- wave64 max-reduce of packed u64 key; result lands in lane 63 ----
// key = (f32 bits of dist << 32) | ~index  -> max key == (max dist, tie: min index)
#define DPP_STEP(CTRL) { \
  int hi=(int)(k>>32), lo=(int)k; \
  int ohi=__builtin_amdgcn_update_dpp(hi,hi,CTRL,0xf,0xf,false); \
  int olo=__builtin_amdgcn_update_dpp(lo,lo,CTRL,0xf,0xf,false); \
  unsigned long long ok=((unsigned long long)(unsigned)ohi<<32)|(unsigned)olo; \
  if (ok>k) k=ok; }

DEV void tr1(int i, const float* __restrict__ in, float* __restrict__ out, int C, int R){
  int r = i / C, c = i - r*C; out[(size_t)c*R + r] = in[i];
}

// ---------------- front kernel: blocks 0..15 fused FPS; the rest prep ----------------
__global__ __launch_bounds__(256)
void k_front(const float* __restrict__ pc, float4* __restrict__ xyz,
             float4* __restrict__ nx0, float4* __restrict__ nx1,
             const float* __restrict__ w00, float* __restrict__ o00,
             const float* __restrict__ w01, float* __restrict__ o01,
             const float* __restrict__ w10, float* __restrict__ o10,
             const float* __restrict__ w11, float* __restrict__ o11,
             const float* __restrict__ w20, float* __restrict__ o20,
             const float* __restrict__ w21, float* __restrict__ o21)
{
  constexpr int N = 4096, NP = 512, NT = 256, NP2 = 64, NW = NT/64, NPR = N/(2*NT);
  if (blockIdx.x >= NB){
    int i = (int)(blockIdx.x - NB)*256 + threadIdx.x;
    if (i < 65536){
      const float* p = pc + (size_t)i*9;
      xyz[i] = make_float4(p[0], p[1], p[2], 0.f);
      return;
    }
    i -= 65536;
    if (i < 576)    { tr1(i, w00, o00, 9, 64);     return; } i -= 576;
    if (i < 8192)   { tr1(i, w01, o01, 64, 128);   return; } i -= 8192;
    if (i < 16768)  { tr1(i, w10, o10, 131, 128);  return; } i -= 16768;
    if (i < 32768)  { tr1(i, w11, o11, 128, 256);  return; } i -= 32768;
    if (i < 132608) { tr1(i, w20, o20, 259, 512);  return; } i -= 132608;
    if (i < 524288) { tr1(i, w21, o21, 512, 1024); return; }
    return;
  }
  // ---------------- FPS: one block per batch, 4 waves, packed-f32 dist ----------------
  __shared__ float4 sp[N];                 // float4 points: 1 ds_read_b128 center fetch
  __shared__ float4 c1p[NP];
  __shared__ unsigned long long exch[2][NW];
  const int b = blockIdx.x, t = threadIdx.x, lane = t & 63, w = t >> 6;
  const float* src = pc + (size_t)b*N*9;
  // pair p: .x -> index t + (2p)*NT, .y -> index t + (2p+1)*NT  (ascending, .x < .y)
  v2f px[NPR], py[NPR], pz[NPR], pd[NPR];
  #pragma unroll
  for (int p=0;p<NPR;p++){
    int i0 = t + (2*p)*NT, i1 = i0 + NT;
    const float* a0 = src + (size_t)i0*9;
    const float* a1 = src + (size_t)i1*9;
    float x0=a0[0], y0=a0[1], z0=a0[2];
    float x1=a1[0], y1=a1[1], z1=a1[2];
    px[p] = (v2f){x0,x1}; py[p] = (v2f){y0,y1}; pz[p] = (v2f){z0,z1};
    pd[p] = (v2f){1e10f,1e10f};
    sp[i0] = make_float4(x0,y0,z0,0.f);
    sp[i1] = make_float4(x1,y1,z1,0.f);
  }
  __syncthreads();
  float cx = sp[0].x, cy = sp[0].y, cz = sp[0].z;
  for (int it=0; it<NP; it++){
    if (t==0){
      nx0[(size_t)b*NP + it] = make_float4(cx,cy,cz,0.f);
      c1p[it] = make_float4(cx,cy,cz,0.f);
    }
    v2f cx2 = {cx,cx}, cy2 = {cy,cy}, cz2 = {cz,cz};
    v2f bm = {-1.f,-1.f};
    #pragma unroll
    for (int p=0;p<NPR;p++){
      v2f d = d2v(px[p]-cx2, py[p]-cy2, pz[p]-cz2);
      v2f nd = __builtin_elementwise_min(pd[p], d);
      pd[p] = nd;
      bm = __builtin_elementwise_max(bm, nd);
    }
    float bv = fmaxf(bm.x, bm.y);
    // recovery: lowest index attaining bv (descending overwrite -> first in order)
    int bj = 0;
    #pragma unroll
    for (int p=NPR-1;p>=0;p--){
      if (pd[p].y == bv) bj = 2*p+1;
      if (pd[p].x == bv) bj = 2*p;
    }
    int bi = t + bj*NT;
    unsigned long long best = ((unsigned long long)__float_as_uint(bv)<<32) | (unsigned)~bi;
    { unsigned long long k = best; DPP_STEP(0x118) DPP_STEP(0x114) DPP_STEP(0x112)
      DPP_STEP(0x111) DPP_STEP(0x142) DPP_STEP(0x143) best = k; }
    if (lane == 63) exch[it&1][w] = best;
    __syncthreads();
    unsigned long long g = exch[it&1][0];
    #pragma unroll
    for (int q=1;q<NW;q++){ unsigned long long e = exch[it&1][q]; if (e > g) g = e; }
    int far = (int)~(unsigned)g;
    float4 c = sp[far];
    cx = c.x; cy = c.y; cz = c.z;
  }
  // ---------------- stage 2: FPS over the 512 stage-1 centers -> 64 ----------------
  {
    float4 p0 = c1p[t], p1 = c1p[t + NT];
    v2f qx = {p0.x,p1.x}, qy = {p0.y,p1.y}, qz = {p0.z,p1.z}, qd = {1e10f,1e10f};
    float ax = c1p[0].x, ay = c1p[0].y, az = c1p[0].z;
    for (int it=0; it<NP2; it++){
      if (t==0) nx1[(size_t)b*NP2 + it] = make_float4(ax,ay,az,0.f);
      v2f d = d2v(qx-(v2f){ax,ax}, qy-(v2f){ay,ay}, qz-(v2f){az,az});
      qd = __builtin_elementwise_min(qd, d);
      float bv = fmaxf(qd.x, qd.y);
      int bj = 1;
      if (qd.x == bv) bj = 0;           // lowest index wins ties (.x = t < .y = t+NT)
      int bi = t + bj*NT;
      unsigned long long best = ((unsigned long long)__float_as_uint(bv)<<32) | (unsigned)~bi;
      { unsigned long long k = best; DPP_STEP(0x118) DPP_STEP(0x114) DPP_STEP(0x112)
        DPP_STEP(0x111) DPP_STEP(0x142) DPP_STEP(0x143) best = k; }
      if (lane == 63) exch[it&1][w] = best;
      __syncthreads();
      unsigned long long g = exch[it&1][0];
      #pragma unroll
      for (int q=1;q<NW;q++){ unsigned long long e = exch[it&1][q]; if (e > g) g = e; }
      int far = (int)~(unsigned)g;
      float4 c = c1p[far];
      ax = c.x; ay = c.y; az = c.z;
    }
  }
}

// ---------------- all three ball queries in one launch (wave-per-group) ----------------
__global__ __launch_bounds__(256)
void k_bq_all(const float4* __restrict__ xyz0, const float4* __restrict__ nx0,
              const float4* __restrict__ nx1,
              int* __restrict__ idx0, int* __restrict__ idx1, int* __restrict__ idx2)
{
  int wid = blockIdx.x*4 + (threadIdx.x >> 6);
  int lane = threadIdx.x & 63;
  const float4* xb; float4 c; int* o; int N, K; float r2;
  if (wid < 8192){
    int b = wid >> 9, s = wid & 511;
    xb = xyz0 + (size_t)b*4096; c = nx0[(size_t)b*512 + s];
    o = idx0 + ((size_t)b*512 + s)*32; N = 4096; K = 32; r2 = 0.01f;
  } else if (wid < 9216){
    int u = wid - 8192; int b = u >> 6, s = u & 63;
    xb = nx0 + (size_t)b*512; c = nx1[(size_t)b*64 + s];
    o = idx1 + ((size_t)b*64 + s)*64; N = 512; K = 64; r2 = 0.04f;
  } else {
    int b = wid - 9216;
    xb = nx1 + (size_t)b*64; c = nx1[(size_t)b*64];
    o = idx2 + (size_t)b*64; N = 64; K = 64; r2 = 0.16f;
  }
  int cnt = 0, first = 0;
  bool have_first = false;
  for (int base = 0; base < N; base += 64){
    float4 p = xb[base + lane];
    float d = d2c(p.x - c.x, p.y - c.y, p.z - c.z);
    bool hit = (d <= r2);
    unsigned long long m = __ballot(hit);
    if (m){
      if (!have_first){ first = base + __ffsll((unsigned long long)m) - 1; have_first = true; }
      if (hit){
        int pos = cnt + __popcll(m & ((1ull << lane) - 1ull));
        if (pos < K) o[pos] = base + lane;
      }
      cnt += __popcll(m);
      if (cnt >= K) break;
    }
  }
  for (int pos = cnt + lane; pos < K; pos += 64) o[pos] = first;
}

// ---------------- SA0 fused: gather + MLP(9->64->128) + maxpool, 8 groups/block ----------------
__global__ __launch_bounds__(256)
void k_sa0(const float4* __restrict__ xyz, const float4* __restrict__ nx0,
           const int* __restrict__ idx0, const float* __restrict__ pc,
           const float* __restrict__ w0tg, const float* __restrict__ g0g, const float* __restrict__ b0g,
           const float* __restrict__ w1tg, const float* __restrict__ g1g, const float* __restrict__ b1g,
           float* __restrict__ f1)
{
  constexpr int K = 32, S = 512, C0 = 64, C1 = 128, G = 8;
  __shared__ float w1t[C0*C1];
  __shared__ float w0t[9*C0];
  __shared__ float gb0[2*C0];
  __shared__ float gb1[2*C1];
  __shared__ float xs[9][K];
  __shared__ float y0[C0][K];
  int t = threadIdx.x;
  for (int i=t;i<C0*C1;i+=256) w1t[i] = w1tg[i];
  for (int i=t;i<9*C0;i+=256)  w0t[i] = w0tg[i];
  if (t < C0){ gb0[t]=g0g[t]; gb0[C0+t]=b0g[t]; }
  if (t < C1){ gb1[t]=g1g[t]; gb1[C1+t]=b1g[t]; }
  int k0 = (t & 7)*4, og = t >> 3;
  for (int gi=0; gi<G; gi++){
    int gid = blockIdx.x*G + gi;
    int b = gid >> 9, s = gid & 511;
    __syncthreads();
    if (t < K){
      int i = idx0[(size_t)gid*K + t];
      float4 cen = nx0[(size_t)b*S + s];
      float4 p = xyz[(size_t)b*N0 + i];
      xs[0][t]=p.x-cen.x; xs[1][t]=p.y-cen.y; xs[2][t]=p.z-cen.z;
      const float* pr = pc + ((size_t)b*N0 + i)*9 + 3;
      #pragma unroll
      for (int f=0;f<6;f++) xs[3+f][t] = pr[f];
    }
    __syncthreads();
    float a0[2][4] = {};
    #pragma unroll
    for (int c=0;c<9;c++){
      float4 xv = *(const float4*)&xs[c][k0];
      #pragma unroll
      for (int j=0;j<2;j++){
        float w = w0t[c*C0 + og*2 + j];
        a0[j][0]+=w*xv.x; a0[j][1]+=w*xv.y; a0[j][2]+=w*xv.z; a0[j][3]+=w*xv.w;
      }
    }
    #pragma unroll
    for (int j=0;j<2;j++){
      int o = og*2 + j;
      float g = gb0[o], bb = gb0[C0+o];
      float4 r;
      r.x=fmaxf(a0[j][0]*g+bb,0.f); r.y=fmaxf(a0[j][1]*g+bb,0.f);
      r.z=fmaxf(a0[j][2]*g+bb,0.f); r.w=fmaxf(a0[j][3]*g+bb,0.f);
      *(float4*)&y0[o][k0] = r;
    }
    __syncthreads();
    float a1[4][4] = {};
    #pragma unroll 4
    for (int c=0;c<C0;c++){
      float4 yv = *(const float4*)&y0[c][k0];
      const float* wp = &w1t[c*C1 + og*4];
      #pragma unroll
      for (int j=0;j<4;j++){
        float w = wp[j];
        a1[j][0]+=w*yv.x; a1[j][1]+=w*yv.y; a1[j][2]+=w*yv.z; a1[j][3]+=w*yv.w;
      }
    }
    #pragma unroll
    for (int j=0;j<4;j++){
      int o = og*4 + j;
      float g = gb1[o], bb = gb1[C1+o];
      float m = fmaxf(fmaxf(a1[j][0]*g+bb, a1[j][1]*g+bb), fmaxf(a1[j][2]*g+bb, a1[j][3]*g+bb));
      m = fmaxf(m, 0.f);
      #pragma unroll
      for (int off=1; off<8; off<<=1) m = fmaxf(m, __shfl_xor(m, off));
      if ((t & 7) == 0) f1[((size_t)b*C1 + o)*S + s] = m;
    }
  }
}

// ---------------- SA1 dense per-point feature GEMM ----------------
__global__ __launch_bounds__(256)
void k_z1(const float* __restrict__ f1, const float* __restrict__ w0t, float* __restrict__ Z1)
{
  int b = blockIdx.z;
  int obase = blockIdx.x*64, ibase = blockIdx.y*64;
  int t = threadIdx.x;
  int i0 = ibase + (t & 15)*4, ol = (t >> 4)*4;
  float acc[4][4] = {};
  #pragma unroll 4
  for (int c=0;c<128;c++){
    float4 fv = *(const float4*)&f1[((size_t)b*128 + c)*512 + i0];
    float4 wv = *(const float4*)&w0t[(size_t)(3+c)*128 + obase + ol];
    float wa[4] = {wv.x, wv.y, wv.z, wv.w};
    float fa[4] = {fv.x, fv.y, fv.z, fv.w};
    #pragma unroll
    for (int j=0;j<4;j++)
      #pragma unroll
      for (int i=0;i<4;i++) acc[j][i] += wa[j]*fa[i];
  }
  #pragma unroll
  for (int j=0;j<4;j++)
    *(float4*)&Z1[((size_t)b*128 + obase + ol + j)*512 + i0] =
        make_float4(acc[j][0], acc[j][1], acc[j][2], acc[j][3]);
}

// ---------------- SA1 fused: gather Z1 + xyz-dot -> y0, MLP1(128->256) + maxpool ----------------
__global__ __launch_bounds__(256)
void k_sa1(const float4* __restrict__ nx0, const float4* __restrict__ nx1,
           const int* __restrict__ idx1, const float* __restrict__ Z1,
           const float* __restrict__ w0t, const float* __restrict__ g0, const float* __restrict__ b0,
           const float* __restrict__ w1t, const float* __restrict__ g1, const float* __restrict__ b1,
           float* __restrict__ f2)
{
  constexpr int K = 64, S = 64, C0 = 128, C1 = 256;
  __shared__ float y0[C0][K];
  __shared__ float gx[3][K];
  __shared__ int sidx[K];
  int gid = blockIdx.x, b = gid >> 6, s = gid & 63;
  int t = threadIdx.x;
  if (t < K) sidx[t] = idx1[(size_t)gid*K + t];
  __syncthreads();
  if (t < K){
    float4 cen = nx1[(size_t)b*S + s];
    float4 p = nx0[(size_t)b*512 + sidx[t]];
    gx[0][t]=p.x-cen.x; gx[1][t]=p.y-cen.y; gx[2][t]=p.z-cen.z;
  }
  __syncthreads();
  int k0 = (t & 15)*4, og = t >> 4;
  {
    float4 x0 = *(const float4*)&gx[0][k0];
    float4 x1 = *(const float4*)&gx[1][k0];
    float4 x2 = *(const float4*)&gx[2][k0];
    int i0=sidx[k0], i1=sidx[k0+1], i2=sidx[k0+2], i3=sidx[k0+3];
    #pragma unroll
    for (int j=0;j<8;j++){
      int o = og*8 + j;
      const float* zr = Z1 + ((size_t)b*C0 + o)*512;
      float wx=w0t[o], wy=w0t[C0+o], wz=w0t[2*C0+o];
      float g=g0[o], bb=b0[o];
      float4 r;
      r.x = fmaxf((zr[i0] + wx*x0.x + wy*x1.x + wz*x2.x)*g + bb, 0.f);
      r.y = fmaxf((zr[i1] + wx*x0.y + wy*x1.y + wz*x2.y)*g + bb, 0.f);
      r.z = fmaxf((zr[i2] + wx*x0.z + wy*x1.z + wz*x2.z)*g + bb, 0.f);
      r.w = fmaxf((zr[i3] + wx*x0.w + wy*x1.w + wz*x2.w)*g + bb, 0.f);
      *(float4*)&y0[o][k0] = r;
    }
  }
  __syncthreads();
  float a1[16][4] = {};
  #pragma unroll 2
  for (int c=0;c<C0;c++){
    float4 yv = *(const float4*)&y0[c][k0];
    const float* wp = &w1t[(size_t)c*C1 + og*16];
    #pragma unroll
    for (int j=0;j<16;j++){
      float w = wp[j];
      a1[j][0]+=w*yv.x; a1[j][1]+=w*yv.y; a1[j][2]+=w*yv.z; a1[j][3]+=w*yv.w;
    }
  }
  #pragma unroll
  for (int j=0;j<16;j++){
    int o = og*16 + j;
    float g=g1[o], bb=b1[o];
    float m = fmaxf(fmaxf(a1[j][0]*g+bb, a1[j][1]*g+bb), fmaxf(a1[j][2]*g+bb, a1[j][3]*g+bb));
    m = fmaxf(m, 0.f);
    #pragma unroll
    for (int off=1; off<16; off<<=1) m = fmaxf(m, __shfl_xor(m, off));
    if ((t & 15) == 0) f2[((size_t)b*C1 + o)*S + s] = m;
  }
}

// ---------------- SA2 gather ----------------
__global__ __launch_bounds__(256)
void k_gather2(const float4* __restrict__ nx1, const int* __restrict__ idx2,
               const float* __restrict__ f2, float* __restrict__ x2)
{
  int b = blockIdx.x, t = threadIdx.x;
  __shared__ int sidx[64];
  if (t < 64) sidx[t] = idx2[b*64 + t];
  __syncthreads();
  float4 cen = nx1[(size_t)b*64];
  float* xo = x2 + (size_t)b*259*64;
  if (t < 64){
    float4 p = nx1[(size_t)b*64 + sidx[t]];
    xo[t] = p.x - cen.x; xo[64 + t] = p.y - cen.y; xo[128 + t] = p.z - cen.z;
  }
  for (int i=t; i<256*64; i+=256){
    int c = i >> 6, k = i & 63;
    xo[(3+c)*64 + k] = f2[((size_t)b*256 + c)*64 + sidx[k]];
  }
}

// ---------------- SA2 layer0 ----------------
__global__ __launch_bounds__(256)
void k_sa2_l0(const float* __restrict__ x2, const float* __restrict__ w0t,
              const float* __restrict__ g0, const float* __restrict__ b0,
              float* __restrict__ y2)
{
  int b = blockIdx.y;
  int obase = blockIdx.x*64;
  int t = threadIdx.x;
  int k0 = (t & 15)*4, ol = (t >> 4)*4;
  const float* xb = x2 + (size_t)b*259*64;
  float acc[4][4] = {};
  #pragma unroll 4
  for (int c=0;c<259;c++){
    float4 xv = *(const float4*)&xb[c*64 + k0];
    float4 wv = *(const float4*)&w0t[(size_t)c*512 + obase + ol];
    float wa[4] = {wv.x, wv.y, wv.z, wv.w};
    float xa[4] = {xv.x, xv.y, xv.z, xv.w};
    #pragma unroll
    for (int j=0;j<4;j++)
      #pragma unroll
      for (int i=0;i<4;i++) acc[j][i] += wa[j]*xa[i];
  }
  #pragma unroll
  for (int j=0;j<4;j++){
    int o = obase + ol + j;
    float g = g0[o], bb = b0[o];
    float4 r;
    r.x=fmaxf(acc[j][0]*g+bb,0.f); r.y=fmaxf(acc[j][1]*g+bb,0.f);
    r.z=fmaxf(acc[j][2]*g+bb,0.f); r.w=fmaxf(acc[j][3]*g+bb,0.f);
    *(float4*)&y2[((size_t)b*512 + o)*64 + k0] = r;
  }
}

// ---------------- SA2 layer1 + maxpool ----------------
__global__ __launch_bounds__(256)
void k_sa2_l1(const float* __restrict__ y2, const float* __restrict__ w1t,
              const float* __restrict__ g1, const float* __restrict__ b1,
              float* __restrict__ f3)
{
  int b = blockIdx.y;
  int obase = blockIdx.x*64;
  int t = threadIdx.x;
  int k0 = (t & 15)*4, ol = (t >> 4)*4;
  const float* yb = y2 + (size_t)b*512*64;
  float acc[4][4] = {};
  #pragma unroll 4
  for (int c=0;c<512;c++){
    float4 yv = *(const float4*)&yb[c*64 + k0];
    float4 wv = *(const float4*)&w1t[(size_t)c*1024 + obase + ol];
    float wa[4] = {wv.x, wv.y, wv.z, wv.w};
    float ya[4] = {yv.x, yv.y, yv.z, yv.w};
    #pragma unroll
    for (int j=0;j<4;j++)
      #pragma unroll
      for (int i=0;i<4;i++) acc[j][i] += wa[j]*ya[i];
  }
  #pragma unroll
  for (int j=0;j<4;j++){
    int o = obase + ol + j;
    float g = g1[o], bb = b1[o];
    float m = fmaxf(fmaxf(acc[j][0]*g+bb, acc[j][1]*g+bb), fmaxf(acc[j][2]*g+bb, acc[j][3]*g+bb));
    m = fmaxf(m, 0.f);
    #pragma unroll
    for (int off=1; off<16; off<<=1) m = fmaxf(m, __shfl_xor(m, off));
    if ((t & 15) == 0) f3[(size_t)b*1024 + o] = m;
  }
}

// ---------------- classifier: wide GEMV layers ----------------
template<bool RELU>
__global__ __launch_bounds__(256)
void k_lin(const float* __restrict__ x, const float* __restrict__ w,
           const float* __restrict__ g, const float* __restrict__ bb,
           float* __restrict__ y, int Cin, int Cout)
{
  __shared__ float xs[1024];
  int b = blockIdx.y, t = threadIdx.x;
  const float* xb = x + (size_t)b*Cin;
  for (int i=t;i<Cin;i+=256) xs[i] = xb[i];
  __syncthreads();
  int o = blockIdx.x*256 + t;
  if (o < Cout){
    const float4* wr = (const float4*)(w + (size_t)o*Cin);
    float acc = 0.f;
    #pragma unroll 8
    for (int c=0;c<Cin/4;c++){
      float4 wv = wr[c]; float4 xv = *(const float4*)&xs[c*4];
      acc += wv.x*xv.x + wv.y*xv.y + wv.z*xv.z + wv.w*xv.w;
    }
    float r;
    if (RELU) r = fmaxf(acc*g[o] + bb[o], 0.f);
    else      r = acc + bb[o];
    y[(size_t)b*Cout + o] = r;
  }
}

extern "C" void kernel_launch(void* const* d_in, const int* in_sizes, int n_in,
                              void* d_out, int out_size, void* d_ws, size_t ws_size,
                              hipStream_t stream)
{
  (void)in_sizes; (void)n_in; (void)out_size; (void)ws_size;
  const float* pc    = (const float*)d_in[0];
  const float* sa0w0 = (const float*)d_in[1];
  const float* sa0g0 = (const float*)d_in[2];
  const float* sa0b0 = (const float*)d_in[3];
  const float* sa0w1 = (const float*)d_in[4];
  const float* sa0g1 = (const float*)d_in[5];
  const float* sa0b1 = (const float*)d_in[6];
  const float* sa1w0 = (const float*)d_in[7];
  const float* sa1g0 = (const float*)d_in[8];
  const float* sa1b0 = (const float*)d_in[9];
  const float* sa1w1 = (const float*)d_in[10];
  const float* sa1g1 = (const float*)d_in[11];
  const float* sa1b1 = (const float*)d_in[12];
  const float* sa2w0 = (const float*)d_in[13];
  const float* sa2g0 = (const float*)d_in[14];
  const float* sa2b0 = (const float*)d_in[15];
  const float* sa2w1 = (const float*)d_in[16];
  const float* sa2g1 = (const float*)d_in[17];
  const float* sa2b1 = (const float*)d_in[18];
  const float* clsw0 = (const float*)d_in[19];
  const float* clsg0 = (const float*)d_in[20];
  const float* clsb0 = (const float*)d_in[21];
  const float* clsw1 = (const float*)d_in[22];
  const float* clsg1 = (const float*)d_in[23];
  const float* clsb1 = (const float*)d_in[24];
  const float* clsw2 = (const float*)d_in[25];
  const float* clsg2 = (const float*)d_in[26];
  const float* clsb2 = (const float*)d_in[27];
  const float* clsw3 = (const float*)d_in[28];
  const float* clsb3 = (const float*)d_in[29];

  char* ws = (char*)d_ws;
  size_t off = 0;
  auto A = [&](size_t bytes)->char* {
    char* p = ws + off;
    off = (off + bytes + 255) & ~(size_t)255;
    return p;
  };
  float4* xyz0 = (float4*)A((size_t)NB*N0*16);
  float4* nx0  = (float4*)A((size_t)NB*512*16);
  float4* nx1  = (float4*)A((size_t)NB*64*16);
  int*   idx0  = (int*)  A((size_t)NB*512*32*4);
  int*   idx1  = (int*)  A((size_t)NB*64*64*4);
  int*   idx2  = (int*)  A((size_t)NB*64*4);
  float* f1    = (float*)A((size_t)NB*128*512*4);
  float* Z1    = (float*)A((size_t)NB*128*512*4);
  float* f2    = (float*)A((size_t)NB*256*64*4);
  float* x2    = (float*)A((size_t)NB*259*64*4);
  float* y2    = (float*)A((size_t)NB*512*64*4);
  float* f3    = (float*)A((size_t)NB*1024*4);
  float* cb0   = (float*)A((size_t)NB*1024*4);
  float* cb1   = (float*)A((size_t)NB*512*4);
  float* cb2   = (float*)A((size_t)NB*128*4);
  float* w0t0  = (float*)A((size_t)9*64*4);
  float* w1t0  = (float*)A((size_t)64*128*4);
  float* w0t1  = (float*)A((size_t)131*128*4);
  float* w1t1  = (float*)A((size_t)128*256*4);
  float* w0t2  = (float*)A((size_t)259*512*4);
  float* w1t2  = (float*)A((size_t)512*1024*4);

  // ---- front: 16 FPS blocks + 3050 prep blocks in ONE launch ----
  k_front<<<NB + 3050, 256, 0, stream>>>(pc, xyz0, nx0, nx1,
      sa0w0, w0t0, sa0w1, w1t0, sa1w0, w0t1, sa1w1, w1t1, sa2w0, w0t2, sa2w1, w1t2);

  // ---- all ball queries ----
  k_bq_all<<<2308, 256, 0, stream>>>(xyz0, nx0, nx1, idx0, idx1, idx2);

  // ---- SA0 ----
  k_sa0<<<(NB*512)/8, 256, 0, stream>>>(xyz0, nx0, idx0, pc,
                                        w0t0, sa0g0, sa0b0, w1t0, sa0g1, sa0b1, f1);
  // ---- SA1 ----
  k_z1<<<dim3(2, 8, NB), 256, 0, stream>>>(f1, w0t1, Z1);
  k_sa1<<<NB*64, 256, 0, stream>>>(nx0, nx1, idx1, Z1,
                                   w0t1, sa1g0, sa1b0, w1t1, sa1g1, sa1b1, f2);
  // ---- SA2 ----
  k_gather2<<<NB, 256, 0, stream>>>(nx1, idx2, f2, x2);
  k_sa2_l0<<<dim3(8, NB), 256, 0, stream>>>(x2, w0t2, sa2g0, sa2b0, y2);
  k_sa2_l1<<<dim3(16, NB), 256, 0, stream>>>(y2, w1t2, sa2g1, sa2b1, f3);
  // ---- classifier ----
  k_lin<true ><<<dim3(4, NB), 256, 0, stream>>>(f3,  clsw0, clsg0, clsb0, cb0, 1024, 1024);
  k_lin<true ><<<dim3(2, NB), 256, 0, stream>>>(cb0, clsw1, clsg1, clsb1, cb1, 1024, 512);
  k_lin<true ><<<dim3(1, NB), 256, 0, stream>>>(cb1, clsw2, clsg2, clsb2, cb2, 512, 128);
  k_lin<false><<<dim3(1, NB), 256, 0, stream>>>(cb2, clsw3, clsb3, clsb3, (float*)d_out, 128, 63);
}